// Round 19
// baseline (219.813 us; speedup 1.0000x reference)
//
#include <hip/hip_runtime.h>
#include <hip/hip_bf16.h>
#include <math.h>

#define DM 1024
#define SEQ 2048
#define DH 64
#define NH 16
#define DMLP 4096
#define BATCH 2
#define ROWS (BATCH*SEQ)   // 4096

typedef __attribute__((ext_vector_type(4))) float f32x4;
typedef __attribute__((ext_vector_type(8))) short bf16x8;
typedef __attribute__((ext_vector_type(4))) unsigned int u32x4;

__device__ __forceinline__ void gl2lds16(const __hip_bfloat16* g, __hip_bfloat16* l) {
  __builtin_amdgcn_global_load_lds(
      (const __attribute__((address_space(1))) void*)g,
      (__attribute__((address_space(3))) void*)l, 16, 0, 0);
}

__device__ __forceinline__ float bfu2f(unsigned short u) {
  union { unsigned int i; float f; } cvt;
  cvt.i = ((unsigned int)u) << 16;
  return cvt.f;
}

__device__ __forceinline__ unsigned short f2bu(float f) {
  __hip_bfloat16 h = __float2bfloat16(f);
  return *reinterpret_cast<unsigned short*>(&h);
}

// ---------------------------------------------------------------------------
// gemm256: C[M,N] = A[M,K] * BT[N,K]^T over K-chunk KS. 256x256 tile, BK=64,
// 512 thr (8 waves 2Mx4N), 4-phase/K-tile counted-vmcnt schedule. LDS 128 KiB.
// Best engine for DEEP K (NT>=16; NT=4 regresses — prologue/drain tail).
//   QKV : <1024,1024,1,0,0,1> grid 4800x1 FLAT; blocks 0..191 = GEMM
//         (bx=id&15, by=id>>4; same A-sharing-mod-8 XCD property); VOUT: V
//         third (n0>=2048) writes V^T straight to vt. Blocks 192..4799 run
//         the wo/w_in/w_out transposes (2 tiles each) on the 64 CUs the
//         192-block GEMM leaves idle — removes the serial w3 prep stage.
//         Transpose tile aliases into As (LDS stays 128 KiB).
//   mlp1: <1024,1024,1,1,1,0> grid (16,16,1)
//   mlp2: <4096,1024,1,0,0,0> grid (16,4,4) -> bf16 partials + ln_res4
// Split output offset: zoff = (z&1)*zs1 + (z>>1)*zs2 elements.
// ---------------------------------------------------------------------------
template<int K, int KS, int OUT_BF16, int BIAS, int RELU, int VOUT>
__global__ __launch_bounds__(512) void gemm256(
    const __hip_bfloat16* __restrict__ A,
    const __hip_bfloat16* __restrict__ BT,
    float* __restrict__ Cf,
    __hip_bfloat16* __restrict__ Cb,
    const float* __restrict__ bias,
    __hip_bfloat16* __restrict__ vt,
    const float* __restrict__ wo, const float* __restrict__ w_in,
    const float* __restrict__ w_out,
    __hip_bfloat16* __restrict__ woT, __hip_bfloat16* __restrict__ w_inT,
    __hip_bfloat16* __restrict__ w_outT,
    int N, long long zs1, long long zs2)
{
  constexpr int NT = KS / 64;
  static_assert(NT >= 2, "pipeline needs >=2 K-tiles");
  __shared__ __align__(16) __hip_bfloat16 As[2][16384];
  __shared__ __align__(16) __hip_bfloat16 Bs[2][16384];
  const int bidx = (int)blockIdx.x;

  if (VOUT && bidx >= 192) {
    // --- fused w3 transpose path (2 x 32x32 tiles per 512-thr block) ---
    float* tbase = (float*)&As[0][0];       // alias: 2*1056 floats = 8.4 KB
    const int half = threadIdx.x >> 8;      // 0/1
    const int tt   = threadIdx.x & 255;
    int tl = (bidx - 192) * 2 + half;
    const float* s; __hip_bfloat16* dd; int KK, NN, bxw;
    if (tl < 1024)      { s = wo;    dd = woT;    KK = DM;   NN = DM;   bxw = 32;  }
    else if (tl < 5120) { tl -= 1024; s = w_in;  dd = w_inT;  KK = DM;   NN = DMLP; bxw = 128; }
    else                { tl -= 5120; s = w_out; dd = w_outT; KK = DMLP; NN = DM;   bxw = 32;  }
    const int n0t = (tl % bxw) * 32, k0t = (tl / bxw) * 32;
    const int tx = tt & 31, ty = tt >> 5;
    float* T = tbase + half * 1056;
    for (int i = ty; i < 32; i += 8)
      T[i*33 + tx] = s[(size_t)(k0t+i)*NN + n0t + tx];
    __syncthreads();
    for (int i = ty; i < 32; i += 8)
      dd[(size_t)(n0t+i)*KK + k0t + tx] = __float2bfloat16(T[tx*33 + i]);
    return;
  }

  const int t    = threadIdx.x;
  const int wave = t >> 6;
  const int lane = t & 63;
  const int col  = lane & 15;
  const int quad = lane >> 4;
  const int m0 = (VOUT ? (bidx & 15) : (int)blockIdx.x) * 256;  // M: XCD-local A reuse
  const int n0 = (VOUT ? (bidx >> 4) : (int)blockIdx.y) * 256;
  const int kz = (int)blockIdx.z * KS;
  const int wm = (wave >> 2) * 128;     // 2 wave-rows of 128
  const int wn = (wave & 3) * 64;       // 4 wave-cols of 64

  const int tr = t >> 3;
  const int tc = (t & 7) ^ (tr & 7);
  const __hip_bfloat16* gA = A  + (size_t)(m0 + tr) * K + kz + tc * 8;
  const __hip_bfloat16* gB = BT + (size_t)(n0 + tr) * K + kz + tc * 8;

  const int sw  = col & 7;
  const int ao0 = ((quad)     ^ sw) * 8;
  const int ao1 = ((4 + quad) ^ sw) * 8;

  f32x4 acc[8][4] = {};

#define STAGE_A(h, u) do {                                                     \
    gl2lds16(gA + (size_t)(h)*128*K + (u)*64,                                  \
             &As[(u)&1][(h)*8192 + wave*512]);                                 \
    gl2lds16(gA + (size_t)(h)*128*K + (u)*64 + (size_t)64*K,                   \
             &As[(u)&1][(h)*8192 + 4096 + wave*512]);                          \
  } while (0)
#define STAGE_B(h, u) do {                                                     \
    gl2lds16(gB + (size_t)(h)*128*K + (u)*64,                                  \
             &Bs[(u)&1][(h)*8192 + wave*512]);                                 \
    gl2lds16(gB + (size_t)(h)*128*K + (u)*64 + (size_t)64*K,                   \
             &Bs[(u)&1][(h)*8192 + 4096 + wave*512]);                          \
  } while (0)
#define LOAD_A(base) do { _Pragma("unroll")                                    \
    for (int i = 0; i < 4; ++i) {                                              \
      af[i][0] = *(const bf16x8*)(pA + (base) + i*1024 + ao0);                 \
      af[i][1] = *(const bf16x8*)(pA + (base) + i*1024 + ao1);                 \
    } } while (0)
#define LOAD_BX(arr, base) do { _Pragma("unroll")                              \
    for (int j = 0; j < 2; ++j) {                                              \
      arr[j][0] = *(const bf16x8*)(pB + (base) + j*1024 + ao0);                \
      arr[j][1] = *(const bf16x8*)(pB + (base) + j*1024 + ao1);                \
    } } while (0)
#define PHASE_TAIL(MB, NB, BARR) do {                                          \
    asm volatile("s_barrier" ::: "memory");                                    \
    asm volatile("s_waitcnt lgkmcnt(0)" ::: "memory");                         \
    __builtin_amdgcn_s_setprio(1);                                             \
    _Pragma("unroll")                                                          \
    for (int kk = 0; kk < 2; ++kk)                                             \
      _Pragma("unroll")                                                        \
      for (int i = 0; i < 4; ++i)                                              \
        _Pragma("unroll")                                                      \
        for (int j = 0; j < 2; ++j)                                            \
          acc[(MB)+i][(NB)+j] = __builtin_amdgcn_mfma_f32_16x16x32_bf16(       \
              af[i][kk], BARR[j][kk], acc[(MB)+i][(NB)+j], 0, 0, 0);           \
    __builtin_amdgcn_s_setprio(0);                                             \
    asm volatile("s_barrier" ::: "memory");                                    \
  } while (0)

  STAGE_A(0, 0); STAGE_B(0, 0); STAGE_A(1, 0); STAGE_B(1, 0);
  STAGE_A(0, 1); STAGE_B(0, 1); STAGE_A(1, 1); STAGE_B(1, 1);
  asm volatile("s_waitcnt vmcnt(8)" ::: "memory");
  asm volatile("s_barrier" ::: "memory");

  #pragma unroll 2
  for (int u = 0; u < NT; ++u) {
    const __hip_bfloat16* pA = As[u & 1] + (wm + col) * 64;
    const __hip_bfloat16* pB = Bs[u & 1] + (wn + col) * 64;
    const bool s2 = (u + 2 < NT);
    bf16x8 af[4][2], bl[2][2], bh[2][2];

    // phase 1: Q00 = A-lo x B-lo (bl kept in regs through p4)
    LOAD_A(0);
    LOAD_BX(bl, 0);
    PHASE_TAIL(0, 0, bl);

    // phase 2: Q01 = A-lo x B-hi. After this barrier, all B reads done.
    LOAD_BX(bh, 2048);
    PHASE_TAIL(0, 2, bh);

    // phase 3: Q11 = A-hi x B-hi; stage B0+B1(u+2) into freed B regions.
    LOAD_A(4096);
    if (s2) { STAGE_B(0, u + 2); STAGE_B(1, u + 2); }
    PHASE_TAIL(4, 2, bh);

    // phase 4: Q10 = A-hi x B-lo(regs); stage A0+A1(u+2); counted vmcnt.
    if (s2) {
      STAGE_A(0, u + 2); STAGE_A(1, u + 2);
      asm volatile("s_waitcnt vmcnt(8)" ::: "memory");
    } else {
      asm volatile("s_waitcnt vmcnt(0)" ::: "memory");
    }
    PHASE_TAIL(4, 0, bl);
  }
#undef STAGE_A
#undef STAGE_B
#undef LOAD_A
#undef LOAD_BX
#undef PHASE_TAIL

  if (VOUT && n0 >= 2048) {
    // V third: write V^T directly. Per (mi,ni): e = (cn-2048)&63 fixed,
    // s = cm&2047 with r=0..3 consecutive -> packed ushort4 (8B aligned).
    const int b = m0 >> 11;            // batch (block-uniform; 2048 rows/batch)
    #pragma unroll
    for (int mi = 0; mi < 8; ++mi) {
      #pragma unroll
      for (int ni = 0; ni < 4; ++ni) {
        const int cn = n0 + wn + ni*16 + col;
        const int vc = cn - 2048;
        const int hh = vc >> 6, e = vc & 63;
        const int cm = m0 + wm + mi*16 + quad*4;
        const int s  = cm & 2047;
        ushort4 o = { f2bu(acc[mi][ni][0]), f2bu(acc[mi][ni][1]),
                      f2bu(acc[mi][ni][2]), f2bu(acc[mi][ni][3]) };
        *(ushort4*)&vt[((size_t)((b*16 + hh)*64 + e))*SEQ + s] = o;
      }
    }
    return;
  }

  const size_t zoff = (size_t)(blockIdx.z & 1) * (size_t)zs1
                    + (size_t)(blockIdx.z >> 1) * (size_t)zs2;
  __hip_bfloat16* Cbz = Cb + zoff;
  float*          Cfz = Cf + zoff;
  #pragma unroll
  for (int mi = 0; mi < 8; ++mi) {
    #pragma unroll
    for (int ni = 0; ni < 4; ++ni) {
      const int cn = n0 + wn + ni*16 + col;
      float bv = 0.f;
      if (BIAS) bv = bias[cn];
      #pragma unroll
      for (int r = 0; r < 4; ++r) {
        const int cm = m0 + wm + mi*16 + quad*4 + r;  // C/D: col=lane&15, row=quad*4+reg
        float v = acc[mi][ni][r];
        if (BIAS) v += bv;
        if (RELU) v = fmaxf(v, 0.f);
        if (OUT_BF16) Cbz[(size_t)cm * N + cn] = __float2bfloat16(v);
        else          Cfz[(size_t)cm * N + cn] = v;
      }
    }
  }
}

// ---------------------------------------------------------------------------
// gemm128: 128x128 tile split-K 2-phase pipeline. Best engine for SHORT K
// (proj: KS=512, NT=8). 64 KiB LDS -> 2 blocks/CU. bf16 split output.
// ---------------------------------------------------------------------------
template<int KS, int SPLIT, int OUT_BF16, int BIAS, int RELU>
__global__ __launch_bounds__(256) void gemm128(
    const __hip_bfloat16* __restrict__ A,
    const __hip_bfloat16* __restrict__ BT,
    float* __restrict__ Cf,
    __hip_bfloat16* __restrict__ Cb,
    const float* __restrict__ bias,
    int N, int K, long long zstride)
{
  constexpr int NT = KS / 64;
  static_assert(NT >= 2, "pipeline needs >=2 K-tiles");
  __shared__ __align__(16) __hip_bfloat16 As[2][8192];
  __shared__ __align__(16) __hip_bfloat16 Bs[2][8192];
  const int t    = threadIdx.x;
  const int wave = t >> 6;
  const int lane = t & 63;
  const int col  = lane & 15;
  const int quad = lane >> 4;
  const int m0 = blockIdx.x * 128;
  const int n0 = blockIdx.y * 128;
  const int kz = (SPLIT > 1) ? (int)blockIdx.z * KS : 0;
  const int wm = (wave >> 1) * 64;
  const int wn = (wave & 1) * 64;

  const int tr = t >> 3;
  const int tc = (t & 7) ^ (tr & 7);
  const __hip_bfloat16* gA = A  + (size_t)(m0 + tr) * K + kz + tc * 8;
  const __hip_bfloat16* gB = BT + (size_t)(n0 + tr) * K + kz + tc * 8;

  const int sw  = col & 7;
  const int ao0 = ((quad)     ^ sw) * 8;
  const int ao1 = ((4 + quad) ^ sw) * 8;

  f32x4 acc[4][4] = {};

#define SA(u) do { _Pragma("unroll")                                           \
    for (int q = 0; q < 4; ++q)                                                \
      gl2lds16(gA + (size_t)(q*32)*K + (u)*64,                                 \
               &As[(u)&1][q*2048 + wave*512]);                                 \
  } while (0)
#define SB(u) do { _Pragma("unroll")                                           \
    for (int q = 0; q < 4; ++q)                                                \
      gl2lds16(gB + (size_t)(q*32)*K + (u)*64,                                 \
               &Bs[(u)&1][q*2048 + wave*512]);                                 \
  } while (0)

  SA(0); SB(0); SA(1);                   // 12 loads in flight

  #pragma unroll 2
  for (int v = 0; v < NT; ++v) {
    const __hip_bfloat16* pA = As[v & 1] + (wm + col) * 64;
    const __hip_bfloat16* pB = Bs[v & 1] + (wn + col) * 64;
    bf16x8 af[4][2], bf[4][2];

    if (v + 1 < NT) {
      SB(v + 1);
      asm volatile("s_waitcnt vmcnt(8)" ::: "memory");
    } else {
      asm volatile("s_waitcnt vmcnt(0)" ::: "memory");
    }
    asm volatile("s_barrier" ::: "memory");
    #pragma unroll
    for (int i = 0; i < 4; ++i) {
      af[i][0] = *(const bf16x8*)(pA + i*1024 + ao0);
      af[i][1] = *(const bf16x8*)(pA + i*1024 + ao1);
    }
    #pragma unroll
    for (int j = 0; j < 2; ++j) {
      bf[j][0] = *(const bf16x8*)(pB + j*1024 + ao0);
      bf[j][1] = *(const bf16x8*)(pB + j*1024 + ao1);
    }
    asm volatile("s_waitcnt lgkmcnt(0)" ::: "memory");
    __builtin_amdgcn_s_setprio(1);
    #pragma unroll
    for (int kk = 0; kk < 2; ++kk)
      #pragma unroll
      for (int i = 0; i < 4; ++i)
        #pragma unroll
        for (int j = 0; j < 2; ++j)
          acc[i][j] = __builtin_amdgcn_mfma_f32_16x16x32_bf16(
              af[i][kk], bf[j][kk], acc[i][j], 0, 0, 0);
    __builtin_amdgcn_s_setprio(0);
    asm volatile("s_barrier" ::: "memory");

    if (v + 2 < NT) SA(v + 2);
    #pragma unroll
    for (int j = 2; j < 4; ++j) {
      bf[j][0] = *(const bf16x8*)(pB + j*1024 + ao0);
      bf[j][1] = *(const bf16x8*)(pB + j*1024 + ao1);
    }
    asm volatile("s_waitcnt lgkmcnt(0)" ::: "memory");
    __builtin_amdgcn_s_setprio(1);
    #pragma unroll
    for (int kk = 0; kk < 2; ++kk)
      #pragma unroll
      for (int i = 0; i < 4; ++i)
        #pragma unroll
        for (int j = 2; j < 4; ++j)
          acc[i][j] = __builtin_amdgcn_mfma_f32_16x16x32_bf16(
              af[i][kk], bf[j][kk], acc[i][j], 0, 0, 0);
    __builtin_amdgcn_s_setprio(0);
    asm volatile("s_barrier" ::: "memory");
  }
#undef SA
#undef SB

  float*          Cfz = (SPLIT > 1) ? (Cf + (size_t)blockIdx.z * zstride) : Cf;
  __hip_bfloat16* Cbz = (SPLIT > 1) ? (Cb + (size_t)blockIdx.z * zstride) : Cb;
  #pragma unroll
  for (int i = 0; i < 4; ++i) {
    #pragma unroll
    for (int j = 0; j < 4; ++j) {
      const int cn = n0 + wn + j*16 + col;
      float bv = 0.f;
      if (BIAS) bv = bias[cn];
      #pragma unroll
      for (int r = 0; r < 4; ++r) {
        const int cm = m0 + wm + i*16 + quad*4 + r;
        float v = acc[i][j][r];
        if (BIAS) v += bv;
        if (RELU) v = fmaxf(v, 0.f);
        if (OUT_BF16) Cbz[(size_t)cm * N + cn] = __float2bfloat16(v);
        else          Cfz[(size_t)cm * N + cn] = v;
      }
    }
  }
}

// ---------------------------------------------------------------------------
// Flash attention v10 (round-16/18 verified config). Register-resident P via
// K-row permutation. LDS 32 KiB -> 5 blocks/CU; grid 1280 blocks = 5/CU.
// Chunking: 16 tiles x 128 rows; njt=2tl+2; grid (bh=32, slot=40).
// tl<4 -> direct write; else partials + finalize.
// ---------------------------------------------------------------------------
__global__ __launch_bounds__(256) void attn_kernel(
    const __hip_bfloat16* __restrict__ qkv,
    const __hip_bfloat16* __restrict__ vt,
    __hip_bfloat16* __restrict__ aout,
    __hip_bfloat16* __restrict__ opart,
    float* __restrict__ lpart)
{
  __shared__ __align__(16) __hip_bfloat16 Ks[2][64*64];
  __shared__ __align__(16) __hip_bfloat16 Vts[2][64*64];

  const int bh = blockIdx.x, b = bh >> 4, h = bh & 15;
  const int t = threadIdx.x, wave = t >> 6, lane = t & 63;
  const int col = lane & 15, quad = lane >> 4;
  const float SC = 0.125f * 1.44269504f;   // 1/sqrt(dh) * log2(e)

  const int r0  = t >> 3;                 // staging dest row within 32-row half
  const int cs0 = (t & 7) ^ (r0 & 7);     // XOR-swizzled chunk (dest-row keyed)
  const int pk0 = ((r0 >> 4) & 1)*32 + ((r0 >> 2) & 3)*8 + (r0 & 3);
  const __hip_bfloat16* kbase = qkv + (size_t)b*SEQ*3072 + 1024 + h*64;
  const __hip_bfloat16* vbase = vt + (size_t)bh*64*SEQ;

#define KISSUE(j0, buf) do {                                                      \
    gl2lds16(kbase + (size_t)((j0) + pk0    )*3072 + cs0*8, &Ks[buf][wave*512]);  \
    gl2lds16(kbase + (size_t)((j0) + pk0 + 4)*3072 + cs0*8, &Ks[buf][2048 + wave*512]); \
  } while (0)
#define VISSUE(j0, buf) do {                                                      \
    gl2lds16(vbase + (size_t)r0*SEQ        + (j0) + cs0*8,  &Vts[buf][wave*512]); \
    gl2lds16(vbase + (size_t)(32 + r0)*SEQ + (j0) + cs0*8,  &Vts[buf][2048 + wave*512]); \
  } while (0)

  // slot -> (chunk c, 128-row tile tl)
  const int y = (int)blockIdx.y;
  int c, tl;
  if (y < 16)      { c = 0; tl = 15 - y; }
  else if (y < 28) { c = 1; tl = 31 - y; }   // tl 15..4
  else if (y < 36) { c = 2; tl = 43 - y; }   // tl 15..8
  else             { c = 3; tl = 51 - y; }   // tl 15..12
  const int jbeg = c * 8;
  const int njt  = 2*tl + 2;
  const int jend = min(jbeg + 8, njt);

  const int i0 = tl * 128;
  const int iw = i0 + wave*32;              // wave's 32 q-rows

  bf16x8 aq[2][2];                          // [ib][kk]
  #pragma unroll
  for (int ib = 0; ib < 2; ib++)
    #pragma unroll
    for (int kk = 0; kk < 2; kk++)
      aq[ib][kk] = *(const bf16x8*)&qkv[((size_t)(b*SEQ + iw + ib*16 + col))*3072 + h*64 + kk*32 + quad*8];

  f32x4 O[4][2] = {};                       // [et][ib]: O^T[e=et*16+quad*4+r][i=col]
  float lsum[2] = {0.f, 0.f};

  KISSUE(jbeg * 64, 0);
  VISSUE(jbeg * 64, 0);
  for (int jt = jbeg; jt < jend; jt++) {
    const int cur = (jt - jbeg) & 1;
    const int j0 = jt * 64;
    const bool pf = (jt + 1 < jend);
    asm volatile("s_barrier" ::: "memory");
    if (pf) {
      KISSUE(j0 + 64, cur ^ 1);
      VISSUE(j0 + 64, cur ^ 1);
      asm volatile("s_waitcnt vmcnt(4)" ::: "memory");   // K(jt)+V(jt) landed
    } else {
      asm volatile("s_waitcnt vmcnt(0)" ::: "memory");
    }

    // QK^T swapped: S[jl][ib][r] = P^T[global j = j0+pi(slot)][i=iw+ib*16+col]
    f32x4 S[4][2] = {};
    __builtin_amdgcn_s_setprio(1);
    #pragma unroll
    for (int kk = 0; kk < 2; kk++) {
      const int sl = ((kk*4 + quad) ^ (col & 7)) * 8;
      #pragma unroll
      for (int jl = 0; jl < 4; jl++) {
        bf16x8 bk = *(const bf16x8*)&Ks[cur][(jl*16 + col)*64 + sl];
        #pragma unroll
        for (int ib = 0; ib < 2; ib++)
          S[jl][ib] = __builtin_amdgcn_mfma_f32_16x16x32_bf16(bk, aq[ib][kk], S[jl][ib], 0, 0, 0);
      }
    }
    __builtin_amdgcn_s_setprio(0);

    // softmax (no-max): p stays in registers, packed to bf16 dword pairs.
    unsigned int pw[2][4][2];
    #pragma unroll
    for (int ib = 0; ib < 2; ib++) {
      const int ig = iw + ib*16 + col;       // this lane's q-row
      if (j0 + 64 > iw + ib*16) {            // mask path (wave/ib-uniform)
        #pragma unroll
        for (int jl = 0; jl < 4; jl++) {
          const int jb = j0 + (jl & 1)*32 + quad*8 + (jl >> 1)*4;  // permuted base
          float p[4];
          #pragma unroll
          for (int r = 0; r < 4; r++) {
            float v = __builtin_amdgcn_exp2f(S[jl][ib][r] * SC);
            if (jb + r > ig) v = 0.f;
            p[r] = v;
            lsum[ib] += v;
          }
          pw[ib][jl][0] = (unsigned int)f2bu(p[0]) | ((unsigned int)f2bu(p[1]) << 16);
          pw[ib][jl][1] = (unsigned int)f2bu(p[2]) | ((unsigned int)f2bu(p[3]) << 16);
        }
      } else {
        #pragma unroll
        for (int jl = 0; jl < 4; jl++) {
          float p[4];
          #pragma unroll
          for (int r = 0; r < 4; r++) {
            p[r] = __builtin_amdgcn_exp2f(S[jl][ib][r] * SC);
            lsum[ib] += p[r];
          }
          pw[ib][jl][0] = (unsigned int)f2bu(p[0]) | ((unsigned int)f2bu(p[1]) << 16);
          pw[ib][jl][1] = (unsigned int)f2bu(p[2]) | ((unsigned int)f2bu(p[3]) << 16);
        }
      }
    }

    // PV swapped: O^T += mfma(A=V^T-frag, B=P^T-frag from REGISTERS)
    __builtin_amdgcn_s_setprio(1);
    #pragma unroll
    for (int kk = 0; kk < 2; kk++) {
      const int sl = ((kk*4 + quad) ^ (col & 7)) * 8;
      bf16x8 ap[2];
      #pragma unroll
      for (int ib = 0; ib < 2; ib++) {
        u32x4 bu = { pw[ib][kk][0], pw[ib][kk][1], pw[ib][kk+2][0], pw[ib][kk+2][1] };
        ap[ib] = __builtin_bit_cast(bf16x8, bu);
      }
      #pragma unroll
      for (int et = 0; et < 4; et++) {
        bf16x8 bv = *(const bf16x8*)&Vts[cur][(et*16 + col)*64 + sl];
        #pragma unroll
        for (int ib = 0; ib < 2; ib++)
          O[et][ib] = __builtin_amdgcn_mfma_f32_16x16x32_bf16(bv, ap[ib], O[et][ib], 0, 0, 0);
      }
    }
    __builtin_amdgcn_s_setprio(0);
  }

  // epilogue: thread holds O[q-row=col][e=et*16+quad*4+r] per ib
  #pragma unroll
  for (int ib = 0; ib < 2; ib++) {
    float s = lsum[ib];
    s += __shfl_xor(s, 16);
    s += __shfl_xor(s, 32);                  // all quads: full row-sum for q-row col
    const int m = b*SEQ + iw + ib*16 + col;
    if (tl < 4) {
      const float inv = __builtin_amdgcn_rcpf(s);
      #pragma unroll
      for (int et = 0; et < 4; et++) {
        ushort4 o = { f2bu(O[et][ib][0]*inv), f2bu(O[et][ib][1]*inv),
                      f2bu(O[et][ib][2]*inv), f2bu(O[et][ib][3]*inv) };
        *(ushort4*)&aout[(size_t)m*DM + h*64 + et*16 + quad*4] = o;
      }
    } else {
      __hip_bfloat16* op = opart + ((size_t)c*ROWS + m)*DM + h*64;
      #pragma unroll
      for (int et = 0; et < 4; et++) {
        ushort4 o = { f2bu(O[et][ib][0]), f2bu(O[et][ib][1]),
                      f2bu(O[et][ib][2]), f2bu(O[et][ib][3]) };
        *(ushort4*)&op[et*16 + quad*4] = o;
      }
      if (quad == 0) lpart[((size_t)c*ROWS + m)*16 + h] = s;
    }
  }
#undef KISSUE
#undef VISSUE
}

// Combine partials for 128-row tiles tl >= 4: aout = (sum_c O) / (sum_c L)
__global__ __launch_bounds__(256) void attn_finalize(
    const __hip_bfloat16* __restrict__ opart,
    const float* __restrict__ lpart,
    __hip_bfloat16* __restrict__ aout)
{
  const int y = blockIdx.x;            // 0..3071 = 2 batches x 12 tiles x 128 rows
  const int b = y / 1536;
  const int rem = y % 1536;
  const int tl = 4 + (rem >> 7);
  const int rr = rem & 127;
  const int m = b*SEQ + tl*128 + rr;
  const int nch = (tl >> 2) + 1;       // 2..4
  const int tid = threadIdx.x;
  const int h = tid >> 4;              // 16 threads per head (64 cols / 4)
  float o0 = 0.f, o1 = 0.f, o2 = 0.f, o3 = 0.f, l = 0.f;
  for (int c = 0; c < nch; ++c) {
    const ushort4 v = ((const ushort4*)(opart + ((size_t)c*ROWS + m)*DM))[tid];
    o0 += bfu2f(v.x); o1 += bfu2f(v.y); o2 += bfu2f(v.z); o3 += bfu2f(v.w);
    l  += lpart[((size_t)c*ROWS + m)*16 + h];
  }
  const float inv = __builtin_amdgcn_rcpf(l);
  __hip_bfloat16* p = aout + (size_t)m*DM + tid*4;
  p[0] = __float2bfloat16(o0 * inv);
  p[1] = __float2bfloat16(o1 * inv);
  p[2] = __float2bfloat16(o2 * inv);
  p[3] = __float2bfloat16(o3 * inv);
}

// ---------------------------------------------------------------------------
// ln_res2: LayerNorm(y0+y1 (bf16 partials))*g + b + residual -> fp32 xout
// + bf16 copy bout. For proj's 2 split-K bf16 partials.
// ---------------------------------------------------------------------------
__global__ __launch_bounds__(256) void ln_res2(
    const __hip_bfloat16* __restrict__ y0,
    const __hip_bfloat16* __restrict__ y1,
    const float* __restrict__ xres,
    float* __restrict__ xout,
    __hip_bfloat16* __restrict__ bout,
    const float* __restrict__ gamma,
    const float* __restrict__ beta)
{
  const int row = blockIdx.x;
  const int t = threadIdx.x;
  const size_t off = (size_t)row*DM;
  const ushort4 a = ((const ushort4*)(y0 + off))[t];
  const ushort4 b = ((const ushort4*)(y1 + off))[t];
  float4 v;
  v.x = bfu2f(a.x) + bfu2f(b.x);
  v.y = bfu2f(a.y) + bfu2f(b.y);
  v.z = bfu2f(a.z) + bfu2f(b.z);
  v.w = bfu2f(a.w) + bfu2f(b.w);
  float s  = v.x + v.y + v.z + v.w;
  float sq = v.x*v.x + v.y*v.y + v.z*v.z + v.w*v.w;
  #pragma unroll
  for (int o = 32; o > 0; o >>= 1) {
    s  += __shfl_down(s, o);
    sq += __shfl_down(sq, o);
  }
  __shared__ float red[8];
  const int wave = t >> 6, lane = t & 63;
  if (lane == 0) { red[wave] = s; red[4 + wave] = sq; }
  __syncthreads();
  s  = red[0] + red[1] + red[2] + red[3];
  sq = red[4] + red[5] + red[6] + red[7];
  const float mu   = s * (1.f/DM);
  const float var  = sq * (1.f/DM) - mu*mu;
  const float rstd = rsqrtf(var + 1e-5f);
  const float4 g  = ((const float4*)gamma)[t];
  const float4 bt = ((const float4*)beta)[t];
  const float4 xr = ((const float4*)(xres + off))[t];
  float4 o;
  o.x = (v.x - mu)*rstd*g.x + bt.x + xr.x;
  o.y = (v.y - mu)*rstd*g.y + bt.y + xr.y;
  o.z = (v.z - mu)*rstd*g.z + bt.z + xr.z;
  o.w = (v.w - mu)*rstd*g.w + bt.w + xr.w;
  ((float4*)(xout + off))[t] = o;
  __hip_bfloat16* bp = bout + off + t*4;
  bp[0] = __float2bfloat16(o.x);
  bp[1] = __float2bfloat16(o.y);
  bp[2] = __float2bfloat16(o.z);
  bp[3] = __float2bfloat16(o.w);
}

// ---------------------------------------------------------------------------
// ln_res4: LayerNorm(y0+y1+y2+y3 (bf16 partials) + bias)*g + b + residual
// -> fp32 xout. For mlp2's 4 split-K bf16 partials.
// ---------------------------------------------------------------------------
__global__ __launch_bounds__(256) void ln_res4(
    const __hip_bfloat16* __restrict__ y0,
    const __hip_bfloat16* __restrict__ y1,
    const __hip_bfloat16* __restrict__ y2,
    const __hip_bfloat16* __restrict__ y3,
    const float* __restrict__ bias,
    const float* __restrict__ xres,
    float* __restrict__ xout,
    const float* __restrict__ gamma,
    const float* __restrict__ beta)
{
  const int row = blockIdx.x;
  const int t = threadIdx.x;
  const size_t off = (size_t)row*DM;
  const ushort4 a = ((const ushort4*)(y0 + off))[t];
  const ushort4 b = ((const ushort4*)(y1 + off))[t];
  const ushort4 cc = ((const ushort4*)(y2 + off))[t];
  const ushort4 d = ((const ushort4*)(y3 + off))[t];
  const float4 bv = ((const float4*)bias)[t];
  float4 v;
  v.x = bfu2f(a.x) + bfu2f(b.x) + bfu2f(cc.x) + bfu2f(d.x) + bv.x;
  v.y = bfu2f(a.y) + bfu2f(b.y) + bfu2f(cc.y) + bfu2f(d.y) + bv.y;
  v.z = bfu2f(a.z) + bfu2f(b.z) + bfu2f(cc.z) + bfu2f(d.z) + bv.z;
  v.w = bfu2f(a.w) + bfu2f(b.w) + bfu2f(cc.w) + bfu2f(d.w) + bv.w;
  float s  = v.x + v.y + v.z + v.w;
  float sq = v.x*v.x + v.y*v.y + v.z*v.z + v.w*v.w;
  #pragma unroll
  for (int o = 32; o > 0; o >>= 1) {
    s  += __shfl_down(s, o);
    sq += __shfl_down(sq, o);
  }
  __shared__ float red[8];
  const int wave = t >> 6, lane = t & 63;
  if (lane == 0) { red[wave] = s; red[4 + wave] = sq; }
  __syncthreads();
  s  = red[0] + red[1] + red[2] + red[3];
  sq = red[4] + red[5] + red[6] + red[7];
  const float mu   = s * (1.f/DM);
  const float var  = sq * (1.f/DM) - mu*mu;
  const float rstd = rsqrtf(var + 1e-5f);
  const float4 g  = ((const float4*)gamma)[t];
  const float4 bt = ((const float4*)beta)[t];
  const float4 xr = ((const float4*)(xres + off))[t];
  float4 o;
  o.x = (v.x - mu)*rstd*g.x + bt.x + xr.x;
  o.y = (v.y - mu)*rstd*g.y + bt.y + xr.y;
  o.z = (v.z - mu)*rstd*g.z + bt.z + xr.z;
  o.w = (v.w - mu)*rstd*g.w + bt.w + xr.w;
  ((float4*)(xout + off))[t] = o;
}

// ---------------------------------------------------------------------------
// prep_all: fused preprocessing (x->bf16 + wq/wk/wv transposes). The wo/w_in/
// w_out transposes moved INTO the QKV launch (they aren't needed until proj,
// and QKV's 192-block grid leaves 64 CUs idle to run them).
//   id < 4096 : x fp32 -> xb bf16 (flat, 1024 elems/block)
//   else      : wq/wk/wv per-head transpose -> wqkvT (3072 tiles)
// ---------------------------------------------------------------------------
__global__ __launch_bounds__(256) void prep_all(
    const float* __restrict__ x,
    const float* __restrict__ wq, const float* __restrict__ wk,
    const float* __restrict__ wv,
    __hip_bfloat16* __restrict__ xb, __hip_bfloat16* __restrict__ wqkvT)
{
  int id = blockIdx.x;
  if (id < 4096) {
    const int i = id*256 + threadIdx.x;
    const float4 v = ((const float4*)x)[i];
    xb[i*4+0] = __float2bfloat16(v.x);
    xb[i*4+1] = __float2bfloat16(v.y);
    xb[i*4+2] = __float2bfloat16(v.z);
    xb[i*4+3] = __float2bfloat16(v.w);
    return;
  }
  id -= 4096;
  __shared__ float tile[32][33];
  const int tx = threadIdx.x & 31, ty = threadIdx.x >> 5;
  // wqkv: z = id>>6 (op*16+head), rem = id&63 -> k0 = (rem>>1)*32, n0 = (rem&1)*32
  const int z = id >> 6, rem = id & 63;
  const int k0 = (rem >> 1) * 32, n0 = (rem & 1) * 32;
  const int op = z >> 4, hh = z & 15;
  const float* srcs[3] = { wq, wk, wv };
  const float* s = srcs[op] + (size_t)hh * DM * DH;
  __hip_bfloat16* d = wqkvT + (size_t)z * DH * DM;
  for (int i = ty; i < 32; i += 8)
    tile[i][tx] = s[(size_t)(k0+i)*DH + n0 + tx];
  __syncthreads();
  for (int i = ty; i < 32; i += 8)
    d[(size_t)(n0+i)*DM + k0 + tx] = __float2bfloat16(tile[tx][i]);
}

extern "C" void kernel_launch(void* const* d_in, const int* in_sizes, int n_in,
                              void* d_out, int out_size, void* d_ws, size_t ws_size,
                              hipStream_t stream)
{
  const float* x     = (const float*)d_in[0];
  const float* wq    = (const float*)d_in[1];
  const float* wk    = (const float*)d_in[2];
  const float* wv    = (const float*)d_in[3];
  const float* wo    = (const float*)d_in[4];
  const float* w_in  = (const float*)d_in[5];
  const float* b_in  = (const float*)d_in[6];
  const float* w_out = (const float*)d_in[7];
  const float* b_out = (const float*)d_in[8];
  const float* g1    = (const float*)d_in[9];
  const float* bt1   = (const float*)d_in[10];
  const float* g2    = (const float*)d_in[11];
  const float* bt2   = (const float*)d_in[12];
  float* out = (float*)d_out;

  // Workspace map (MiB; PEAK 112 MiB).
  //   0-8 xb (dead after QKV) -> attn_o reuses 0-8
  //   8-14 wqkvT | 14-16 woT | 16-24 w_inT | 24-32 w_outT
  //   32-56 qkvb (Q/K sections used; V section unwritten) + 56-64 vtb
  //     (both dead after attn chunks)
  //   64-96 Opart[4][ROWS][DM] bf16 (attn -> finalize; dead after finalize)
  //   96-97 Lpart[4][ROWS][16] f32  (dead after finalize)
  //   proj bf16 partials (2x8 MiB): {32-40, 40-48} (over dead qkvb; dead
  //     after ln_res2)
  //   x1 72-88 | x1b 88-96 (over dead Opart) | hbuf 32-64 (over dead pp*)
  //   mlp2 bf16 partials (4x8 MiB): {0-8, 8-16, 88-96, 96-104}
  char* ws = (char*)d_ws;
  __hip_bfloat16* xb     = (__hip_bfloat16*)(ws + 0);
  __hip_bfloat16* wqkvT  = (__hip_bfloat16*)(ws + 8388608);
  __hip_bfloat16* woT    = (__hip_bfloat16*)(ws + 14680064);
  __hip_bfloat16* w_inT  = (__hip_bfloat16*)(ws + 16777216);
  __hip_bfloat16* w_outT = (__hip_bfloat16*)(ws + 25165824);
  __hip_bfloat16* qkvb   = (__hip_bfloat16*)(ws + 33554432);
  __hip_bfloat16* vtb    = (__hip_bfloat16*)(ws + 58720256);
  __hip_bfloat16* attn_o = (__hip_bfloat16*)(ws + 0);         // over dead xb
  __hip_bfloat16* opart  = (__hip_bfloat16*)(ws + 67108864);  // 64-96 MiB
  float*          lpart  = (float*)(ws + 100663296);          // 96-97 MiB
  __hip_bfloat16* pp0    = (__hip_bfloat16*)(ws + 33554432);  // proj partial z=0 (32 MiB)
  __hip_bfloat16* pp1    = (__hip_bfloat16*)(ws + 41943040);  // z=1 (40 MiB)
  float*          x1     = (float*)(ws + 75497472);    // 72 MiB
  __hip_bfloat16* x1b    = (__hip_bfloat16*)(ws + 92274688);  // 88 MiB
  __hip_bfloat16* hbuf   = (__hip_bfloat16*)(ws + 33554432);  // 32 MiB
  __hip_bfloat16* mp0    = (__hip_bfloat16*)(ws + 0);         // mlp2 partial z=0
  __hip_bfloat16* mp1    = (__hip_bfloat16*)(ws + 8388608);   // z=1 (8 MiB)
  __hip_bfloat16* mp2    = (__hip_bfloat16*)(ws + 92274688);  // z=2 (88 MiB)
  __hip_bfloat16* mp3    = (__hip_bfloat16*)(ws + 100663296); // z=3 (96 MiB)

  const long long PPZ  = 8388608LL / 2;                    // 8 MiB in bf16 elems
  const long long MZS1 = 8388608LL / 2;                    // 8 MiB in bf16 elems
  const long long MZS2 = 92274688LL / 2;                   // 88 MiB in bf16 elems

  // prep: x->bf16 + wqkv transposes (7168 blocks); w3 moved into QKV launch
  prep_all<<<7168, 256, 0, stream>>>(x, wq, wk, wv, xb, wqkvT);

  // QKV: 256^2 4-phase kernel, flat grid 4800 blocks: 0..191 = GEMM (16x12,
  // V third -> vtb direct), 192..4799 = wo/w_in/w_out transposes running on
  // the 64 CUs the GEMM leaves idle.
  gemm256<DM,DM,1,0,0,1><<<dim3(4800, 1, 1), 512, 0, stream>>>(
      xb, wqkvT, nullptr, qkvb, nullptr, vtb,
      wo, w_in, w_out, woT, w_inT, w_outT, 3072, 0, 0);
  // attn: chunked 128-row tiles, grid (bh=32, 40 chunk-slots) = 1280 blocks = 5/CU
  attn_kernel<<<dim3(BATCH*NH, 40), 256, 0, stream>>>(qkvb, vtb, attn_o, opart, lpart);
  // combine partials for tiles tl >= 4 (2 x 12 x 128 = 3072 rows)
  attn_finalize<<<3072, 256, 0, stream>>>(opart, lpart, attn_o);
  // proj: 128^2 2-phase split-K=2 (short-K engine), bf16 partials {32,40} MiB
  gemm128<512,2,1,0,0><<<dim3(ROWS/128, DM/128, 2), 256, 0, stream>>>(attn_o, woT, nullptr, pp0, nullptr, DM, DM, PPZ);
  ln_res2<<<ROWS, 256, 0, stream>>>(pp0, pp1, x, x1, x1b, g1, bt1);
  // mlp1: 256^2 4-phase kernel, grid (16, 16) = 256 blocks
  gemm256<DM,DM,1,1,1,0><<<dim3(ROWS/256, DMLP/256, 1), 512, 0, stream>>>(
      x1b, w_inT, nullptr, hbuf, b_in, nullptr,
      nullptr, nullptr, nullptr, nullptr, nullptr, nullptr, DMLP, 0, 0);
  // mlp2: 256^2 4-phase split-K=4 (deep-K engine, NT=16), grid (16, 4, 4);
  // bf16 partials at {0, 8, 88, 96} MiB via zoff = (z&1)*MZS1 + (z>>1)*MZS2
  gemm256<DMLP,DM,1,0,0,0><<<dim3(ROWS/256, DM/256, 4), 512, 0, stream>>>(
      hbuf, w_outT, nullptr, mp0, nullptr, nullptr,
      nullptr, nullptr, nullptr, nullptr, nullptr, nullptr, DM, MZS1, MZS2);
  ln_res4<<<ROWS, 256, 0, stream>>>(mp0, mp1, mp2, mp3, b_out, x1, out, g2, bt2);
}

// Round 21
// 209.696 us; speedup vs baseline: 1.0482x; 1.0482x over previous
//
#include <hip/hip_runtime.h>
#include <hip/hip_bf16.h>
#include <math.h>

#define DM 1024
#define SEQ 2048
#define DH 64
#define NH 16
#define DMLP 4096
#define BATCH 2
#define ROWS (BATCH*SEQ)   // 4096

typedef __attribute__((ext_vector_type(4))) float f32x4;
typedef __attribute__((ext_vector_type(8))) short bf16x8;
typedef __attribute__((ext_vector_type(4))) unsigned int u32x4;

__device__ __forceinline__ void gl2lds16(const __hip_bfloat16* g, __hip_bfloat16* l) {
  __builtin_amdgcn_global_load_lds(
      (const __attribute__((address_space(1))) void*)g,
      (__attribute__((address_space(3))) void*)l, 16, 0, 0);
}

__device__ __forceinline__ float bfu2f(unsigned short u) {
  union { unsigned int i; float f; } cvt;
  cvt.i = ((unsigned int)u) << 16;
  return cvt.f;
}

__device__ __forceinline__ unsigned short f2bu(float f) {
  __hip_bfloat16 h = __float2bfloat16(f);
  return *reinterpret_cast<unsigned short*>(&h);
}

// ---------------------------------------------------------------------------
// gemm256: C[M,N] = A[M,K] * BT[N,K]^T over K-chunk KS. 256x256 tile, BK=64,
// 512 thr (8 waves 2Mx4N), 4-phase/K-tile counted-vmcnt schedule. LDS 128 KiB.
// Best engine for DEEP K (NT>=16; NT=4 regresses — prologue/drain tail).
//   QKV : <1024,1024,1,0,0,1> grid (16,12,1); VOUT: V third (n0>=2048)
//         writes V^T straight to vt[bh*64+e][s] (packed ushort4, s=cm&2047).
//   mlp1: <1024,1024,1,1,1,0> grid (16,16,1)
//   mlp2: <4096,1024,1,0,0,0> grid (16,4,4) -> bf16 partials + ln_res4
// Split output offset: zoff = (z&1)*zs1 + (z>>1)*zs2 elements.
// (round-19 lesson: do NOT fuse heterogeneous light blocks into this kernel —
//  they inherit its 128 KiB LDS footprint and serialize at 1 block/CU.)
// ---------------------------------------------------------------------------
template<int K, int KS, int OUT_BF16, int BIAS, int RELU, int VOUT>
__global__ __launch_bounds__(512) void gemm256(
    const __hip_bfloat16* __restrict__ A,
    const __hip_bfloat16* __restrict__ BT,
    float* __restrict__ Cf,
    __hip_bfloat16* __restrict__ Cb,
    const float* __restrict__ bias,
    __hip_bfloat16* __restrict__ vt,
    int N, long long zs1, long long zs2)
{
  constexpr int NT = KS / 64;
  static_assert(NT >= 2, "pipeline needs >=2 K-tiles");
  __shared__ __align__(16) __hip_bfloat16 As[2][16384];
  __shared__ __align__(16) __hip_bfloat16 Bs[2][16384];
  const int t    = threadIdx.x;
  const int wave = t >> 6;
  const int lane = t & 63;
  const int col  = lane & 15;
  const int quad = lane >> 4;
  const int m0 = blockIdx.x * 256;      // M on x: XCD-local A reuse (gridDim.x=16)
  const int n0 = blockIdx.y * 256;
  const int kz = (int)blockIdx.z * KS;
  const int wm = (wave >> 2) * 128;     // 2 wave-rows of 128
  const int wn = (wave & 3) * 64;       // 4 wave-cols of 64

  const int tr = t >> 3;
  const int tc = (t & 7) ^ (tr & 7);
  const __hip_bfloat16* gA = A  + (size_t)(m0 + tr) * K + kz + tc * 8;
  const __hip_bfloat16* gB = BT + (size_t)(n0 + tr) * K + kz + tc * 8;

  const int sw  = col & 7;
  const int ao0 = ((quad)     ^ sw) * 8;
  const int ao1 = ((4 + quad) ^ sw) * 8;

  f32x4 acc[8][4] = {};

#define STAGE_A(h, u) do {                                                     \
    gl2lds16(gA + (size_t)(h)*128*K + (u)*64,                                  \
             &As[(u)&1][(h)*8192 + wave*512]);                                 \
    gl2lds16(gA + (size_t)(h)*128*K + (u)*64 + (size_t)64*K,                   \
             &As[(u)&1][(h)*8192 + 4096 + wave*512]);                          \
  } while (0)
#define STAGE_B(h, u) do {                                                     \
    gl2lds16(gB + (size_t)(h)*128*K + (u)*64,                                  \
             &Bs[(u)&1][(h)*8192 + wave*512]);                                 \
    gl2lds16(gB + (size_t)(h)*128*K + (u)*64 + (size_t)64*K,                   \
             &Bs[(u)&1][(h)*8192 + 4096 + wave*512]);                          \
  } while (0)
#define LOAD_A(base) do { _Pragma("unroll")                                    \
    for (int i = 0; i < 4; ++i) {                                              \
      af[i][0] = *(const bf16x8*)(pA + (base) + i*1024 + ao0);                 \
      af[i][1] = *(const bf16x8*)(pA + (base) + i*1024 + ao1);                 \
    } } while (0)
#define LOAD_BX(arr, base) do { _Pragma("unroll")                              \
    for (int j = 0; j < 2; ++j) {                                              \
      arr[j][0] = *(const bf16x8*)(pB + (base) + j*1024 + ao0);                \
      arr[j][1] = *(const bf16x8*)(pB + (base) + j*1024 + ao1);                \
    } } while (0)
#define PHASE_TAIL(MB, NB, BARR) do {                                          \
    asm volatile("s_barrier" ::: "memory");                                    \
    asm volatile("s_waitcnt lgkmcnt(0)" ::: "memory");                         \
    __builtin_amdgcn_s_setprio(1);                                             \
    _Pragma("unroll")                                                          \
    for (int kk = 0; kk < 2; ++kk)                                             \
      _Pragma("unroll")                                                        \
      for (int i = 0; i < 4; ++i)                                              \
        _Pragma("unroll")                                                      \
        for (int j = 0; j < 2; ++j)                                            \
          acc[(MB)+i][(NB)+j] = __builtin_amdgcn_mfma_f32_16x16x32_bf16(       \
              af[i][kk], BARR[j][kk], acc[(MB)+i][(NB)+j], 0, 0, 0);           \
    __builtin_amdgcn_s_setprio(0);                                             \
    asm volatile("s_barrier" ::: "memory");                                    \
  } while (0)

  STAGE_A(0, 0); STAGE_B(0, 0); STAGE_A(1, 0); STAGE_B(1, 0);
  STAGE_A(0, 1); STAGE_B(0, 1); STAGE_A(1, 1); STAGE_B(1, 1);
  asm volatile("s_waitcnt vmcnt(8)" ::: "memory");
  asm volatile("s_barrier" ::: "memory");

  #pragma unroll 2
  for (int u = 0; u < NT; ++u) {
    const __hip_bfloat16* pA = As[u & 1] + (wm + col) * 64;
    const __hip_bfloat16* pB = Bs[u & 1] + (wn + col) * 64;
    const bool s2 = (u + 2 < NT);
    bf16x8 af[4][2], bl[2][2], bh[2][2];

    // phase 1: Q00 = A-lo x B-lo (bl kept in regs through p4)
    LOAD_A(0);
    LOAD_BX(bl, 0);
    PHASE_TAIL(0, 0, bl);

    // phase 2: Q01 = A-lo x B-hi. After this barrier, all B reads done.
    LOAD_BX(bh, 2048);
    PHASE_TAIL(0, 2, bh);

    // phase 3: Q11 = A-hi x B-hi; stage B0+B1(u+2) into freed B regions.
    LOAD_A(4096);
    if (s2) { STAGE_B(0, u + 2); STAGE_B(1, u + 2); }
    PHASE_TAIL(4, 2, bh);

    // phase 4: Q10 = A-hi x B-lo(regs); stage A0+A1(u+2); counted vmcnt.
    if (s2) {
      STAGE_A(0, u + 2); STAGE_A(1, u + 2);
      asm volatile("s_waitcnt vmcnt(8)" ::: "memory");
    } else {
      asm volatile("s_waitcnt vmcnt(0)" ::: "memory");
    }
    PHASE_TAIL(4, 0, bl);
  }
#undef STAGE_A
#undef STAGE_B
#undef LOAD_A
#undef LOAD_BX
#undef PHASE_TAIL

  if (VOUT && n0 >= 2048) {
    // V third: write V^T directly. Per (mi,ni): e = (cn-2048)&63 fixed,
    // s = cm&2047 with r=0..3 consecutive -> packed ushort4 (8B aligned).
    const int b = m0 >> 11;            // batch (block-uniform; 2048 rows/batch)
    #pragma unroll
    for (int mi = 0; mi < 8; ++mi) {
      #pragma unroll
      for (int ni = 0; ni < 4; ++ni) {
        const int cn = n0 + wn + ni*16 + col;
        const int vc = cn - 2048;
        const int hh = vc >> 6, e = vc & 63;
        const int cm = m0 + wm + mi*16 + quad*4;
        const int s  = cm & 2047;
        ushort4 o = { f2bu(acc[mi][ni][0]), f2bu(acc[mi][ni][1]),
                      f2bu(acc[mi][ni][2]), f2bu(acc[mi][ni][3]) };
        *(ushort4*)&vt[((size_t)((b*16 + hh)*64 + e))*SEQ + s] = o;
      }
    }
    return;
  }

  const size_t zoff = (size_t)(blockIdx.z & 1) * (size_t)zs1
                    + (size_t)(blockIdx.z >> 1) * (size_t)zs2;
  __hip_bfloat16* Cbz = Cb + zoff;
  float*          Cfz = Cf + zoff;
  #pragma unroll
  for (int mi = 0; mi < 8; ++mi) {
    #pragma unroll
    for (int ni = 0; ni < 4; ++ni) {
      const int cn = n0 + wn + ni*16 + col;
      float bv = 0.f;
      if (BIAS) bv = bias[cn];
      #pragma unroll
      for (int r = 0; r < 4; ++r) {
        const int cm = m0 + wm + mi*16 + quad*4 + r;  // C/D: col=lane&15, row=quad*4+reg
        float v = acc[mi][ni][r];
        if (BIAS) v += bv;
        if (RELU) v = fmaxf(v, 0.f);
        if (OUT_BF16) Cbz[(size_t)cm * N + cn] = __float2bfloat16(v);
        else          Cfz[(size_t)cm * N + cn] = v;
      }
    }
  }
}

// ---------------------------------------------------------------------------
// gemm128: 128x128 tile split-K 2-phase pipeline. Best engine for SHORT K
// (proj: KS=512, NT=8). 64 KiB LDS -> 2 blocks/CU. bf16 split output.
// ---------------------------------------------------------------------------
template<int KS, int SPLIT, int OUT_BF16, int BIAS, int RELU>
__global__ __launch_bounds__(256) void gemm128(
    const __hip_bfloat16* __restrict__ A,
    const __hip_bfloat16* __restrict__ BT,
    float* __restrict__ Cf,
    __hip_bfloat16* __restrict__ Cb,
    const float* __restrict__ bias,
    int N, int K, long long zstride)
{
  constexpr int NT = KS / 64;
  static_assert(NT >= 2, "pipeline needs >=2 K-tiles");
  __shared__ __align__(16) __hip_bfloat16 As[2][8192];
  __shared__ __align__(16) __hip_bfloat16 Bs[2][8192];
  const int t    = threadIdx.x;
  const int wave = t >> 6;
  const int lane = t & 63;
  const int col  = lane & 15;
  const int quad = lane >> 4;
  const int m0 = blockIdx.x * 128;
  const int n0 = blockIdx.y * 128;
  const int kz = (SPLIT > 1) ? (int)blockIdx.z * KS : 0;
  const int wm = (wave >> 1) * 64;
  const int wn = (wave & 1) * 64;

  const int tr = t >> 3;
  const int tc = (t & 7) ^ (tr & 7);
  const __hip_bfloat16* gA = A  + (size_t)(m0 + tr) * K + kz + tc * 8;
  const __hip_bfloat16* gB = BT + (size_t)(n0 + tr) * K + kz + tc * 8;

  const int sw  = col & 7;
  const int ao0 = ((quad)     ^ sw) * 8;
  const int ao1 = ((4 + quad) ^ sw) * 8;

  f32x4 acc[4][4] = {};

#define SA(u) do { _Pragma("unroll")                                           \
    for (int q = 0; q < 4; ++q)                                                \
      gl2lds16(gA + (size_t)(q*32)*K + (u)*64,                                 \
               &As[(u)&1][q*2048 + wave*512]);                                 \
  } while (0)
#define SB(u) do { _Pragma("unroll")                                           \
    for (int q = 0; q < 4; ++q)                                                \
      gl2lds16(gB + (size_t)(q*32)*K + (u)*64,                                 \
               &Bs[(u)&1][q*2048 + wave*512]);                                 \
  } while (0)

  SA(0); SB(0); SA(1);                   // 12 loads in flight

  #pragma unroll 2
  for (int v = 0; v < NT; ++v) {
    const __hip_bfloat16* pA = As[v & 1] + (wm + col) * 64;
    const __hip_bfloat16* pB = Bs[v & 1] + (wn + col) * 64;
    bf16x8 af[4][2], bf[4][2];

    if (v + 1 < NT) {
      SB(v + 1);
      asm volatile("s_waitcnt vmcnt(8)" ::: "memory");
    } else {
      asm volatile("s_waitcnt vmcnt(0)" ::: "memory");
    }
    asm volatile("s_barrier" ::: "memory");
    #pragma unroll
    for (int i = 0; i < 4; ++i) {
      af[i][0] = *(const bf16x8*)(pA + i*1024 + ao0);
      af[i][1] = *(const bf16x8*)(pA + i*1024 + ao1);
    }
    #pragma unroll
    for (int j = 0; j < 2; ++j) {
      bf[j][0] = *(const bf16x8*)(pB + j*1024 + ao0);
      bf[j][1] = *(const bf16x8*)(pB + j*1024 + ao1);
    }
    asm volatile("s_waitcnt lgkmcnt(0)" ::: "memory");
    __builtin_amdgcn_s_setprio(1);
    #pragma unroll
    for (int kk = 0; kk < 2; ++kk)
      #pragma unroll
      for (int i = 0; i < 4; ++i)
        #pragma unroll
        for (int j = 0; j < 2; ++j)
          acc[i][j] = __builtin_amdgcn_mfma_f32_16x16x32_bf16(
              af[i][kk], bf[j][kk], acc[i][j], 0, 0, 0);
    __builtin_amdgcn_s_setprio(0);
    asm volatile("s_barrier" ::: "memory");

    if (v + 2 < NT) SA(v + 2);
    #pragma unroll
    for (int j = 2; j < 4; ++j) {
      bf[j][0] = *(const bf16x8*)(pB + j*1024 + ao0);
      bf[j][1] = *(const bf16x8*)(pB + j*1024 + ao1);
    }
    asm volatile("s_waitcnt lgkmcnt(0)" ::: "memory");
    __builtin_amdgcn_s_setprio(1);
    #pragma unroll
    for (int kk = 0; kk < 2; ++kk)
      #pragma unroll
      for (int i = 0; i < 4; ++i)
        #pragma unroll
        for (int j = 2; j < 4; ++j)
          acc[i][j] = __builtin_amdgcn_mfma_f32_16x16x32_bf16(
              af[i][kk], bf[j][kk], acc[i][j], 0, 0, 0);
    __builtin_amdgcn_s_setprio(0);
    asm volatile("s_barrier" ::: "memory");
  }
#undef SA
#undef SB

  float*          Cfz = (SPLIT > 1) ? (Cf + (size_t)blockIdx.z * zstride) : Cf;
  __hip_bfloat16* Cbz = (SPLIT > 1) ? (Cb + (size_t)blockIdx.z * zstride) : Cb;
  #pragma unroll
  for (int i = 0; i < 4; ++i) {
    #pragma unroll
    for (int j = 0; j < 4; ++j) {
      const int cn = n0 + wn + j*16 + col;
      float bv = 0.f;
      if (BIAS) bv = bias[cn];
      #pragma unroll
      for (int r = 0; r < 4; ++r) {
        const int cm = m0 + wm + i*16 + quad*4 + r;
        float v = acc[i][j][r];
        if (BIAS) v += bv;
        if (RELU) v = fmaxf(v, 0.f);
        if (OUT_BF16) Cbz[(size_t)cm * N + cn] = __float2bfloat16(v);
        else          Cfz[(size_t)cm * N + cn] = v;
      }
    }
  }
}

// ---------------------------------------------------------------------------
// Flash attention v10 (round-16/18 verified config). Register-resident P via
// K-row permutation. LDS 32 KiB -> 5 blocks/CU; grid 1280 blocks = 5/CU.
// Chunking: 16 tiles x 128 rows; njt=2tl+2; grid (bh=32, slot=40).
// tl<4 -> direct write; else partials + finalize.
// ---------------------------------------------------------------------------
__global__ __launch_bounds__(256) void attn_kernel(
    const __hip_bfloat16* __restrict__ qkv,
    const __hip_bfloat16* __restrict__ vt,
    __hip_bfloat16* __restrict__ aout,
    __hip_bfloat16* __restrict__ opart,
    float* __restrict__ lpart)
{
  __shared__ __align__(16) __hip_bfloat16 Ks[2][64*64];
  __shared__ __align__(16) __hip_bfloat16 Vts[2][64*64];

  const int bh = blockIdx.x, b = bh >> 4, h = bh & 15;
  const int t = threadIdx.x, wave = t >> 6, lane = t & 63;
  const int col = lane & 15, quad = lane >> 4;
  const float SC = 0.125f * 1.44269504f;   // 1/sqrt(dh) * log2(e)

  const int r0  = t >> 3;                 // staging dest row within 32-row half
  const int cs0 = (t & 7) ^ (r0 & 7);     // XOR-swizzled chunk (dest-row keyed)
  const int pk0 = ((r0 >> 4) & 1)*32 + ((r0 >> 2) & 3)*8 + (r0 & 3);
  const __hip_bfloat16* kbase = qkv + (size_t)b*SEQ*3072 + 1024 + h*64;
  const __hip_bfloat16* vbase = vt + (size_t)bh*64*SEQ;

#define KISSUE(j0, buf) do {                                                      \
    gl2lds16(kbase + (size_t)((j0) + pk0    )*3072 + cs0*8, &Ks[buf][wave*512]);  \
    gl2lds16(kbase + (size_t)((j0) + pk0 + 4)*3072 + cs0*8, &Ks[buf][2048 + wave*512]); \
  } while (0)
#define VISSUE(j0, buf) do {                                                      \
    gl2lds16(vbase + (size_t)r0*SEQ        + (j0) + cs0*8,  &Vts[buf][wave*512]); \
    gl2lds16(vbase + (size_t)(32 + r0)*SEQ + (j0) + cs0*8,  &Vts[buf][2048 + wave*512]); \
  } while (0)

  // slot -> (chunk c, 128-row tile tl)
  const int y = (int)blockIdx.y;
  int c, tl;
  if (y < 16)      { c = 0; tl = 15 - y; }
  else if (y < 28) { c = 1; tl = 31 - y; }   // tl 15..4
  else if (y < 36) { c = 2; tl = 43 - y; }   // tl 15..8
  else             { c = 3; tl = 51 - y; }   // tl 15..12
  const int jbeg = c * 8;
  const int njt  = 2*tl + 2;
  const int jend = min(jbeg + 8, njt);

  const int i0 = tl * 128;
  const int iw = i0 + wave*32;              // wave's 32 q-rows

  bf16x8 aq[2][2];                          // [ib][kk]
  #pragma unroll
  for (int ib = 0; ib < 2; ib++)
    #pragma unroll
    for (int kk = 0; kk < 2; kk++)
      aq[ib][kk] = *(const bf16x8*)&qkv[((size_t)(b*SEQ + iw + ib*16 + col))*3072 + h*64 + kk*32 + quad*8];

  f32x4 O[4][2] = {};                       // [et][ib]: O^T[e=et*16+quad*4+r][i=col]
  float lsum[2] = {0.f, 0.f};

  KISSUE(jbeg * 64, 0);
  VISSUE(jbeg * 64, 0);
  for (int jt = jbeg; jt < jend; jt++) {
    const int cur = (jt - jbeg) & 1;
    const int j0 = jt * 64;
    const bool pf = (jt + 1 < jend);
    asm volatile("s_barrier" ::: "memory");
    if (pf) {
      KISSUE(j0 + 64, cur ^ 1);
      VISSUE(j0 + 64, cur ^ 1);
      asm volatile("s_waitcnt vmcnt(4)" ::: "memory");   // K(jt)+V(jt) landed
    } else {
      asm volatile("s_waitcnt vmcnt(0)" ::: "memory");
    }

    // QK^T swapped: S[jl][ib][r] = P^T[global j = j0+pi(slot)][i=iw+ib*16+col]
    f32x4 S[4][2] = {};
    __builtin_amdgcn_s_setprio(1);
    #pragma unroll
    for (int kk = 0; kk < 2; kk++) {
      const int sl = ((kk*4 + quad) ^ (col & 7)) * 8;
      #pragma unroll
      for (int jl = 0; jl < 4; jl++) {
        bf16x8 bk = *(const bf16x8*)&Ks[cur][(jl*16 + col)*64 + sl];
        #pragma unroll
        for (int ib = 0; ib < 2; ib++)
          S[jl][ib] = __builtin_amdgcn_mfma_f32_16x16x32_bf16(bk, aq[ib][kk], S[jl][ib], 0, 0, 0);
      }
    }
    __builtin_amdgcn_s_setprio(0);

    // softmax (no-max): p stays in registers, packed to bf16 dword pairs.
    unsigned int pw[2][4][2];
    #pragma unroll
    for (int ib = 0; ib < 2; ib++) {
      const int ig = iw + ib*16 + col;       // this lane's q-row
      if (j0 + 64 > iw + ib*16) {            // mask path (wave/ib-uniform)
        #pragma unroll
        for (int jl = 0; jl < 4; jl++) {
          const int jb = j0 + (jl & 1)*32 + quad*8 + (jl >> 1)*4;  // permuted base
          float p[4];
          #pragma unroll
          for (int r = 0; r < 4; r++) {
            float v = __builtin_amdgcn_exp2f(S[jl][ib][r] * SC);
            if (jb + r > ig) v = 0.f;
            p[r] = v;
            lsum[ib] += v;
          }
          pw[ib][jl][0] = (unsigned int)f2bu(p[0]) | ((unsigned int)f2bu(p[1]) << 16);
          pw[ib][jl][1] = (unsigned int)f2bu(p[2]) | ((unsigned int)f2bu(p[3]) << 16);
        }
      } else {
        #pragma unroll
        for (int jl = 0; jl < 4; jl++) {
          float p[4];
          #pragma unroll
          for (int r = 0; r < 4; r++) {
            p[r] = __builtin_amdgcn_exp2f(S[jl][ib][r] * SC);
            lsum[ib] += p[r];
          }
          pw[ib][jl][0] = (unsigned int)f2bu(p[0]) | ((unsigned int)f2bu(p[1]) << 16);
          pw[ib][jl][1] = (unsigned int)f2bu(p[2]) | ((unsigned int)f2bu(p[3]) << 16);
        }
      }
    }

    // PV swapped: O^T += mfma(A=V^T-frag, B=P^T-frag from REGISTERS)
    __builtin_amdgcn_s_setprio(1);
    #pragma unroll
    for (int kk = 0; kk < 2; kk++) {
      const int sl = ((kk*4 + quad) ^ (col & 7)) * 8;
      bf16x8 ap[2];
      #pragma unroll
      for (int ib = 0; ib < 2; ib++) {
        u32x4 bu = { pw[ib][kk][0], pw[ib][kk][1], pw[ib][kk+2][0], pw[ib][kk+2][1] };
        ap[ib] = __builtin_bit_cast(bf16x8, bu);
      }
      #pragma unroll
      for (int et = 0; et < 4; et++) {
        bf16x8 bv = *(const bf16x8*)&Vts[cur][(et*16 + col)*64 + sl];
        #pragma unroll
        for (int ib = 0; ib < 2; ib++)
          O[et][ib] = __builtin_amdgcn_mfma_f32_16x16x32_bf16(bv, ap[ib], O[et][ib], 0, 0, 0);
      }
    }
    __builtin_amdgcn_s_setprio(0);
  }

  // epilogue: thread holds O[q-row=col][e=et*16+quad*4+r] per ib
  #pragma unroll
  for (int ib = 0; ib < 2; ib++) {
    float s = lsum[ib];
    s += __shfl_xor(s, 16);
    s += __shfl_xor(s, 32);                  // all quads: full row-sum for q-row col
    const int m = b*SEQ + iw + ib*16 + col;
    if (tl < 4) {
      const float inv = __builtin_amdgcn_rcpf(s);
      #pragma unroll
      for (int et = 0; et < 4; et++) {
        ushort4 o = { f2bu(O[et][ib][0]*inv), f2bu(O[et][ib][1]*inv),
                      f2bu(O[et][ib][2]*inv), f2bu(O[et][ib][3]*inv) };
        *(ushort4*)&aout[(size_t)m*DM + h*64 + et*16 + quad*4] = o;
      }
    } else {
      __hip_bfloat16* op = opart + ((size_t)c*ROWS + m)*DM + h*64;
      #pragma unroll
      for (int et = 0; et < 4; et++) {
        ushort4 o = { f2bu(O[et][ib][0]), f2bu(O[et][ib][1]),
                      f2bu(O[et][ib][2]), f2bu(O[et][ib][3]) };
        *(ushort4*)&op[et*16 + quad*4] = o;
      }
      if (quad == 0) lpart[((size_t)c*ROWS + m)*16 + h] = s;
    }
  }
#undef KISSUE
#undef VISSUE
}

// Combine partials for 128-row tiles tl >= 4: aout = (sum_c O) / (sum_c L)
__global__ __launch_bounds__(256) void attn_finalize(
    const __hip_bfloat16* __restrict__ opart,
    const float* __restrict__ lpart,
    __hip_bfloat16* __restrict__ aout)
{
  const int y = blockIdx.x;            // 0..3071 = 2 batches x 12 tiles x 128 rows
  const int b = y / 1536;
  const int rem = y % 1536;
  const int tl = 4 + (rem >> 7);
  const int rr = rem & 127;
  const int m = b*SEQ + tl*128 + rr;
  const int nch = (tl >> 2) + 1;       // 2..4
  const int tid = threadIdx.x;
  const int h = tid >> 4;              // 16 threads per head (64 cols / 4)
  float o0 = 0.f, o1 = 0.f, o2 = 0.f, o3 = 0.f, l = 0.f;
  for (int c = 0; c < nch; ++c) {
    const ushort4 v = ((const ushort4*)(opart + ((size_t)c*ROWS + m)*DM))[tid];
    o0 += bfu2f(v.x); o1 += bfu2f(v.y); o2 += bfu2f(v.z); o3 += bfu2f(v.w);
    l  += lpart[((size_t)c*ROWS + m)*16 + h];
  }
  const float inv = __builtin_amdgcn_rcpf(l);
  __hip_bfloat16* p = aout + (size_t)m*DM + tid*4;
  p[0] = __float2bfloat16(o0 * inv);
  p[1] = __float2bfloat16(o1 * inv);
  p[2] = __float2bfloat16(o2 * inv);
  p[3] = __float2bfloat16(o3 * inv);
}

// ---------------------------------------------------------------------------
// ln_res2: LayerNorm(y0+y1 (bf16 partials))*g + b + residual -> fp32 xout
// + bf16 copy bout. For proj's 2 split-K bf16 partials.
// ---------------------------------------------------------------------------
__global__ __launch_bounds__(256) void ln_res2(
    const __hip_bfloat16* __restrict__ y0,
    const __hip_bfloat16* __restrict__ y1,
    const float* __restrict__ xres,
    float* __restrict__ xout,
    __hip_bfloat16* __restrict__ bout,
    const float* __restrict__ gamma,
    const float* __restrict__ beta)
{
  const int row = blockIdx.x;
  const int t = threadIdx.x;
  const size_t off = (size_t)row*DM;
  const ushort4 a = ((const ushort4*)(y0 + off))[t];
  const ushort4 b = ((const ushort4*)(y1 + off))[t];
  float4 v;
  v.x = bfu2f(a.x) + bfu2f(b.x);
  v.y = bfu2f(a.y) + bfu2f(b.y);
  v.z = bfu2f(a.z) + bfu2f(b.z);
  v.w = bfu2f(a.w) + bfu2f(b.w);
  float s  = v.x + v.y + v.z + v.w;
  float sq = v.x*v.x + v.y*v.y + v.z*v.z + v.w*v.w;
  #pragma unroll
  for (int o = 32; o > 0; o >>= 1) {
    s  += __shfl_down(s, o);
    sq += __shfl_down(sq, o);
  }
  __shared__ float red[8];
  const int wave = t >> 6, lane = t & 63;
  if (lane == 0) { red[wave] = s; red[4 + wave] = sq; }
  __syncthreads();
  s  = red[0] + red[1] + red[2] + red[3];
  sq = red[4] + red[5] + red[6] + red[7];
  const float mu   = s * (1.f/DM);
  const float var  = sq * (1.f/DM) - mu*mu;
  const float rstd = rsqrtf(var + 1e-5f);
  const float4 g  = ((const float4*)gamma)[t];
  const float4 bt = ((const float4*)beta)[t];
  const float4 xr = ((const float4*)(xres + off))[t];
  float4 o;
  o.x = (v.x - mu)*rstd*g.x + bt.x + xr.x;
  o.y = (v.y - mu)*rstd*g.y + bt.y + xr.y;
  o.z = (v.z - mu)*rstd*g.z + bt.z + xr.z;
  o.w = (v.w - mu)*rstd*g.w + bt.w + xr.w;
  ((float4*)(xout + off))[t] = o;
  __hip_bfloat16* bp = bout + off + t*4;
  bp[0] = __float2bfloat16(o.x);
  bp[1] = __float2bfloat16(o.y);
  bp[2] = __float2bfloat16(o.z);
  bp[3] = __float2bfloat16(o.w);
}

// ---------------------------------------------------------------------------
// ln_res4: LayerNorm(y0+y1+y2+y3 (bf16 partials) + bias)*g + b + residual
// -> fp32 xout. For mlp2's 4 split-K bf16 partials.
// ---------------------------------------------------------------------------
__global__ __launch_bounds__(256) void ln_res4(
    const __hip_bfloat16* __restrict__ y0,
    const __hip_bfloat16* __restrict__ y1,
    const __hip_bfloat16* __restrict__ y2,
    const __hip_bfloat16* __restrict__ y3,
    const float* __restrict__ bias,
    const float* __restrict__ xres,
    float* __restrict__ xout,
    const float* __restrict__ gamma,
    const float* __restrict__ beta)
{
  const int row = blockIdx.x;
  const int t = threadIdx.x;
  const size_t off = (size_t)row*DM;
  const ushort4 a = ((const ushort4*)(y0 + off))[t];
  const ushort4 b = ((const ushort4*)(y1 + off))[t];
  const ushort4 cc = ((const ushort4*)(y2 + off))[t];
  const ushort4 d = ((const ushort4*)(y3 + off))[t];
  const float4 bv = ((const float4*)bias)[t];
  float4 v;
  v.x = bfu2f(a.x) + bfu2f(b.x) + bfu2f(cc.x) + bfu2f(d.x) + bv.x;
  v.y = bfu2f(a.y) + bfu2f(b.y) + bfu2f(cc.y) + bfu2f(d.y) + bv.y;
  v.z = bfu2f(a.z) + bfu2f(b.z) + bfu2f(cc.z) + bfu2f(d.z) + bv.z;
  v.w = bfu2f(a.w) + bfu2f(b.w) + bfu2f(cc.w) + bfu2f(d.w) + bv.w;
  float s  = v.x + v.y + v.z + v.w;
  float sq = v.x*v.x + v.y*v.y + v.z*v.z + v.w*v.w;
  #pragma unroll
  for (int o = 32; o > 0; o >>= 1) {
    s  += __shfl_down(s, o);
    sq += __shfl_down(sq, o);
  }
  __shared__ float red[8];
  const int wave = t >> 6, lane = t & 63;
  if (lane == 0) { red[wave] = s; red[4 + wave] = sq; }
  __syncthreads();
  s  = red[0] + red[1] + red[2] + red[3];
  sq = red[4] + red[5] + red[6] + red[7];
  const float mu   = s * (1.f/DM);
  const float var  = sq * (1.f/DM) - mu*mu;
  const float rstd = rsqrtf(var + 1e-5f);
  const float4 g  = ((const float4*)gamma)[t];
  const float4 bt = ((const float4*)beta)[t];
  const float4 xr = ((const float4*)(xres + off))[t];
  float4 o;
  o.x = (v.x - mu)*rstd*g.x + bt.x + xr.x;
  o.y = (v.y - mu)*rstd*g.y + bt.y + xr.y;
  o.z = (v.z - mu)*rstd*g.z + bt.z + xr.z;
  o.w = (v.w - mu)*rstd*g.w + bt.w + xr.w;
  ((float4*)(xout + off))[t] = o;
}

// ---------------------------------------------------------------------------
// prep_all: fused preprocessing — one launch replaces cvt_bf16 +
// transpose_wqkv + transpose_w3 (all independent; block-uniform branch;
// homogeneous 256-thread/8KB blocks so occupancy stays high):
//   id <  4096 : x fp32 -> xb bf16 (flat, 1024 elems/block)
//   id <  7168 : wq/wk/wv per-head transpose -> wqkvT
//   else       : wo/w_in/w_out transpose -> woT/w_inT/w_outT (9216 tiles)
// ---------------------------------------------------------------------------
__global__ __launch_bounds__(256) void prep_all(
    const float* __restrict__ x,
    const float* __restrict__ wq, const float* __restrict__ wk,
    const float* __restrict__ wv,
    const float* __restrict__ wo, const float* __restrict__ w_in,
    const float* __restrict__ w_out,
    __hip_bfloat16* __restrict__ xb, __hip_bfloat16* __restrict__ wqkvT,
    __hip_bfloat16* __restrict__ woT, __hip_bfloat16* __restrict__ w_inT,
    __hip_bfloat16* __restrict__ w_outT)
{
  int id = blockIdx.x;
  if (id < 4096) {
    const int i = id*256 + threadIdx.x;
    const float4 v = ((const float4*)x)[i];
    xb[i*4+0] = __float2bfloat16(v.x);
    xb[i*4+1] = __float2bfloat16(v.y);
    xb[i*4+2] = __float2bfloat16(v.z);
    xb[i*4+3] = __float2bfloat16(v.w);
    return;
  }
  id -= 4096;
  __shared__ float tile[32][33];
  const int tx = threadIdx.x & 31, ty = threadIdx.x >> 5;
  if (id < 3072) {
    // wqkv: z = id>>6 (op*16+head), rem = id&63 -> k0 = (rem>>1)*32, n0 = (rem&1)*32
    const int z = id >> 6, rem = id & 63;
    const int k0 = (rem >> 1) * 32, n0 = (rem & 1) * 32;
    const int op = z >> 4, hh = z & 15;
    const float* srcs[3] = { wq, wk, wv };
    const float* s = srcs[op] + (size_t)hh * DM * DH;
    __hip_bfloat16* d = wqkvT + (size_t)z * DH * DM;
    for (int i = ty; i < 32; i += 8)
      tile[i][tx] = s[(size_t)(k0+i)*DH + n0 + tx];
    __syncthreads();
    for (int i = ty; i < 32; i += 8)
      d[(size_t)(n0+i)*DM + k0 + tx] = __float2bfloat16(tile[tx][i]);
    return;
  }
  id -= 3072;
  const float* s; __hip_bfloat16* d; int K, N, bx;
  if (id < 1024)      { s = wo;    d = woT;    K = DM;   N = DM;   bx = 32;  }
  else if (id < 5120) { id -= 1024; s = w_in;  d = w_inT;  K = DM;   N = DMLP; bx = 128; }
  else                { id -= 5120; s = w_out; d = w_outT; K = DMLP; N = DM;   bx = 32;  }
  const int n0 = (id % bx) * 32, k0 = (id / bx) * 32;
  for (int i = ty; i < 32; i += 8)
    tile[i][tx] = s[(size_t)(k0+i)*N + n0 + tx];
  __syncthreads();
  for (int i = ty; i < 32; i += 8)
    d[(size_t)(n0+i)*K + k0 + tx] = __float2bfloat16(tile[tx][i]);
}

extern "C" void kernel_launch(void* const* d_in, const int* in_sizes, int n_in,
                              void* d_out, int out_size, void* d_ws, size_t ws_size,
                              hipStream_t stream)
{
  const float* x     = (const float*)d_in[0];
  const float* wq    = (const float*)d_in[1];
  const float* wk    = (const float*)d_in[2];
  const float* wv    = (const float*)d_in[3];
  const float* wo    = (const float*)d_in[4];
  const float* w_in  = (const float*)d_in[5];
  const float* b_in  = (const float*)d_in[6];
  const float* w_out = (const float*)d_in[7];
  const float* b_out = (const float*)d_in[8];
  const float* g1    = (const float*)d_in[9];
  const float* bt1   = (const float*)d_in[10];
  const float* g2    = (const float*)d_in[11];
  const float* bt2   = (const float*)d_in[12];
  float* out = (float*)d_out;

  // Workspace map (MiB; PEAK 112 MiB).
  //   0-8 xb (dead after QKV) -> attn_o reuses 0-8
  //   8-14 wqkvT | 14-16 woT | 16-24 w_inT | 24-32 w_outT
  //   32-56 qkvb (Q/K sections used; V section unwritten) + 56-64 vtb
  //     (both dead after attn chunks)
  //   64-96 Opart[4][ROWS][DM] bf16 (attn -> finalize; dead after finalize)
  //   96-97 Lpart[4][ROWS][16] f32  (dead after finalize)
  //   proj bf16 partials (2x8 MiB): {32-40, 40-48} (over dead qkvb; dead
  //     after ln_res2)
  //   x1 72-88 | x1b 88-96 (over dead Opart) | hbuf 32-64 (over dead pp*)
  //   mlp2 bf16 partials (4x8 MiB): {0-8, 8-16, 88-96, 96-104}
  char* ws = (char*)d_ws;
  __hip_bfloat16* xb     = (__hip_bfloat16*)(ws + 0);
  __hip_bfloat16* wqkvT  = (__hip_bfloat16*)(ws + 8388608);
  __hip_bfloat16* woT    = (__hip_bfloat16*)(ws + 14680064);
  __hip_bfloat16* w_inT  = (__hip_bfloat16*)(ws + 16777216);
  __hip_bfloat16* w_outT = (__hip_bfloat16*)(ws + 25165824);
  __hip_bfloat16* qkvb   = (__hip_bfloat16*)(ws + 33554432);
  __hip_bfloat16* vtb    = (__hip_bfloat16*)(ws + 58720256);
  __hip_bfloat16* attn_o = (__hip_bfloat16*)(ws + 0);         // over dead xb
  __hip_bfloat16* opart  = (__hip_bfloat16*)(ws + 67108864);  // 64-96 MiB
  float*          lpart  = (float*)(ws + 100663296);          // 96-97 MiB
  __hip_bfloat16* pp0    = (__hip_bfloat16*)(ws + 33554432);  // proj partial z=0 (32 MiB)
  __hip_bfloat16* pp1    = (__hip_bfloat16*)(ws + 41943040);  // z=1 (40 MiB)
  float*          x1     = (float*)(ws + 75497472);    // 72 MiB
  __hip_bfloat16* x1b    = (__hip_bfloat16*)(ws + 92274688);  // 88 MiB
  __hip_bfloat16* hbuf   = (__hip_bfloat16*)(ws + 33554432);  // 32 MiB
  __hip_bfloat16* mp0    = (__hip_bfloat16*)(ws + 0);         // mlp2 partial z=0
  __hip_bfloat16* mp1    = (__hip_bfloat16*)(ws + 8388608);   // z=1 (8 MiB)
  __hip_bfloat16* mp2    = (__hip_bfloat16*)(ws + 92274688);  // z=2 (88 MiB)
  __hip_bfloat16* mp3    = (__hip_bfloat16*)(ws + 100663296); // z=3 (96 MiB)

  const long long PPZ  = 8388608LL / 2;                    // 8 MiB in bf16 elems
  const long long MZS1 = 8388608LL / 2;                    // 8 MiB in bf16 elems
  const long long MZS2 = 92274688LL / 2;                   // 88 MiB in bf16 elems

  // fused prep: x->bf16 + all weight transposes in ONE launch (16384 blocks)
  prep_all<<<16384, 256, 0, stream>>>(x, wq, wk, wv, wo, w_in, w_out,
                                      xb, wqkvT, woT, w_inT, w_outT);

  // QKV: 256^2 4-phase kernel, grid (16, 12); V third written transposed
  // straight to vtb (VOUT=1) -> no transpose_v pass.
  gemm256<DM,DM,1,0,0,1><<<dim3(ROWS/256, 3072/256, 1), 512, 0, stream>>>(xb, wqkvT, nullptr, qkvb, nullptr, vtb, 3072, 0, 0);
  // attn: chunked 128-row tiles, grid (bh=32, 40 chunk-slots) = 1280 blocks = 5/CU
  attn_kernel<<<dim3(BATCH*NH, 40), 256, 0, stream>>>(qkvb, vtb, attn_o, opart, lpart);
  // combine partials for tiles tl >= 4 (2 x 12 x 128 = 3072 rows)
  attn_finalize<<<3072, 256, 0, stream>>>(opart, lpart, attn_o);
  // proj: 128^2 2-phase split-K=2 (short-K engine), bf16 partials {32,40} MiB
  gemm128<512,2,1,0,0><<<dim3(ROWS/128, DM/128, 2), 256, 0, stream>>>(attn_o, woT, nullptr, pp0, nullptr, DM, DM, PPZ);
  ln_res2<<<ROWS, 256, 0, stream>>>(pp0, pp1, x, x1, x1b, g1, bt1);
  // mlp1: 256^2 4-phase kernel, grid (16, 16) = 256 blocks
  gemm256<DM,DM,1,1,1,0><<<dim3(ROWS/256, DMLP/256, 1), 512, 0, stream>>>(x1b, w_inT, nullptr, hbuf, b_in, nullptr, DMLP, 0, 0);
  // mlp2: 256^2 4-phase split-K=4 (deep-K engine, NT=16), grid (16, 4, 4);
  // bf16 partials at {0, 8, 88, 96} MiB via zoff = (z&1)*MZS1 + (z>>1)*MZS2
  gemm256<DMLP,DM,1,0,0,0><<<dim3(ROWS/256, DM/256, 4), 512, 0, stream>>>(hbuf, w_outT, nullptr, mp0, nullptr, nullptr, DM, MZS1, MZS2);
  ln_res4<<<ROWS, 256, 0, stream>>>(mp0, mp1, mp2, mp3, b_out, x1, out, g2, bt2);
}